// Round 2
// baseline (710.174 us; speedup 1.0000x reference)
//
#include <hip/hip_runtime.h>
#include <stdint.h>

typedef unsigned short ushortT;
typedef __attribute__((ext_vector_type(8))) short short8;
typedef __attribute__((ext_vector_type(4))) float float4_;

#define HH 4
#define FF 32
#define HFD 128
#define F_IN 128
#define EDGE_DIM 64
#define HIDDEN 256
#define BB 64
#define MLE 1500
#define NN 96000
#define EEc 600000
#define CAP 32

__device__ __forceinline__ float bf_lo(uint32_t u){ return __uint_as_float(u << 16); }
__device__ __forceinline__ float bf_hi(uint32_t u){ return __uint_as_float(u & 0xffff0000u); }
__device__ __forceinline__ uint32_t f2bf(float f){
    uint32_t u = __float_as_uint(f);
    return (u + 0x7fffu + ((u >> 16) & 1u)) >> 16;
}
__device__ __forceinline__ short8 cvt8(const float* p){
    float4_ x0 = *(const float4_*)p;
    float4_ x1 = *(const float4_*)(p + 4);
    short8 r;
    r[0]=(short)f2bf(x0[0]); r[1]=(short)f2bf(x0[1]); r[2]=(short)f2bf(x0[2]); r[3]=(short)f2bf(x0[3]);
    r[4]=(short)f2bf(x1[0]); r[5]=(short)f2bf(x1[1]); r[6]=(short)f2bf(x1[2]); r[7]=(short)f2bf(x1[3]);
    return r;
}

// ---------------------------------------------------------------------------
// K1: bridges (fp32 in).  csrc[b,hf]=(ins@Wsrc+bsrc)*a_src ; ctrg likewise.
//     cedge in LDS, then M[b,d,h] = sum_f W_edge[d,h*32+f] * cedge[b,h*32+f]
// grid: 64 blocks x 128 threads
// ---------------------------------------------------------------------------
__global__ void k_bridge(const float* ins, const float* Wsrc, const float* bsrc,
                         const float* Wtrg, const float* btrg,
                         const float* Wedg, const float* bedg,
                         const float* a_src, const float* a_trg, const float* a_edge,
                         const float* W_edge,
                         float* csrc, float* ctrg, float* Mout)
{
    __shared__ float ins_s[HIDDEN];
    __shared__ float ce_s[HFD];
    int b = blockIdx.x, t = threadIdx.x;  // t in [0,128)
    const float* ip = ins + b * HIDDEN;
    ins_s[t]       = ip[t];
    ins_s[t + 128] = ip[t + 128];
    __syncthreads();
    float as = 0.f, at = 0.f, ae = 0.f;
    for (int k = 0; k < HIDDEN; k++){
        float iv = ins_s[k];
        as += iv * Wsrc[k*HFD + t];
        at += iv * Wtrg[k*HFD + t];
        ae += iv * Wedg[k*HFD + t];
    }
    csrc[b*HFD + t] = (as + bsrc[t]) * a_src[t];
    ctrg[b*HFD + t] = (at + btrg[t]) * a_trg[t];
    ce_s[t] = (ae + bedg[t]) * a_edge[t];
    __syncthreads();
    #pragma unroll
    for (int rep = 0; rep < 2; rep++){
        int idx = t + rep * 128;      // 0..255
        int d = idx >> 2, h = idx & 3;
        float acc = 0.f;
        #pragma unroll
        for (int f = 0; f < FF; f++)
            acc += W_edge[d*HFD + h*FF + f] * ce_s[h*FF + f];
        Mout[b*256 + d*4 + h] = acc;
    }
}

// ---------------------------------------------------------------------------
// K_t: WcatT[c][d] = bf16( c<128 ? W_proj[d][c] : W_skip[d][c-128] )
// grid: 128 blocks x 256 threads  (32768 elements)
// ---------------------------------------------------------------------------
__global__ void k_transpose(const float* Wp, const float* Wsk, ushortT* WcatT)
{
    int idx = blockIdx.x * 256 + threadIdx.x;
    int c = idx >> 7;          // 0..255
    int d = idx & 127;         // 0..127
    float v = (c < 128) ? Wp[d*128 + c] : Wsk[d*128 + (c - 128)];
    WcatT[c*128 + d] = (ushortT)f2bf(v);
}

// ---------------------------------------------------------------------------
// K2: [96000 x 128] @ [128 x 256] MFMA GEMM (fp32 x -> bf16 frags) ->
//     proj (cols 0..127, bf16), skip (cols 128..255, bf16).
// grid: 1500 blocks x 256 threads; wave tile 16x256
// ---------------------------------------------------------------------------
__global__ __launch_bounds__(256) void k_gemm(const float* x, const ushortT* WcatT,
                                              ushortT* proj, ushortT* skip)
{
    int t = threadIdx.x;
    int w = t >> 6, lane = t & 63;
    int q = lane >> 4, n16 = lane & 15;
    size_t arow = (size_t)blockIdx.x * 64 + w * 16 + n16;

    float4_ acc[16];
    #pragma unroll
    for (int j = 0; j < 16; j++) acc[j] = (float4_){0.f, 0.f, 0.f, 0.f};

    #pragma unroll
    for (int kk = 0; kk < 4; kk++){
        short8 a = cvt8(x + arow * 128 + kk*32 + q*8);
        #pragma unroll
        for (int j = 0; j < 16; j++){
            short8 b = *(const short8*)(WcatT + (size_t)(j*16 + n16) * 128 + kk*32 + q*8);
            acc[j] = __builtin_amdgcn_mfma_f32_16x16x32_bf16(a, b, acc[j], 0, 0, 0);
        }
    }

    size_t rbase = (size_t)blockIdx.x * 64 + w * 16 + q * 4;
    #pragma unroll
    for (int j = 0; j < 16; j++){
        int c = j*16 + n16;
        ushortT* dst = (c < 128) ? proj : skip;
        int cc = c & 127;
        #pragma unroll
        for (int r = 0; r < 4; r++)
            dst[(rbase + r) * 128 + cc] = (ushortT)f2bf(acc[j][r]);
    }
}

// ---------------------------------------------------------------------------
// K3: per-node scores. s_src[n,h] = sum_f proj[n,h,f]*csrc[b,h,f]
// grid: 375 blocks x 256 threads (one thread per node)
// ---------------------------------------------------------------------------
__global__ __launch_bounds__(256) void k_scores(const ushortT* proj, const float* csrc,
                                                const float* ctrg, float* s_src, float* s_trg)
{
    int n = blockIdx.x * 256 + threadIdx.x;
    int b = n / MLE;
    const uint32_t* pr = (const uint32_t*)(proj + (size_t)n * 128);
    const float* cs = csrc + b * HFD;
    const float* ct = ctrg + b * HFD;
    float ss[HH] = {0,0,0,0}, st[HH] = {0,0,0,0};
    #pragma unroll
    for (int i = 0; i < 64; i++){
        uint32_t v = pr[i];
        float lo = bf_lo(v), hi = bf_hi(v);
        int c = 2*i, h = i >> 4;
        ss[h] += lo * cs[c] + hi * cs[c+1];
        st[h] += lo * ct[c] + hi * ct[c+1];
    }
    float4_ o1 = {ss[0], ss[1], ss[2], ss[3]};
    float4_ o2 = {st[0], st[1], st[2], st[3]};
    *(float4_*)(s_src + (size_t)n*4) = o1;
    *(float4_*)(s_trg + (size_t)n*4) = o2;
}

// ---------------------------------------------------------------------------
// K4: per-edge scores + exp + adjacency build (edge-id-only entries).
// grid: ceil(E/256) x 256
// ---------------------------------------------------------------------------
__global__ __launch_bounds__(256) void k_edges(const int* eidx, const int* bids,
    const float* edges, const float* M, const float* s_src, const float* s_trg,
    float* ex, int* cnt_src, int* cnt_trg, uint32_t* adj_src, uint32_t* adj_trg)
{
    int e = blockIdx.x * 256 + threadIdx.x;
    if (e >= EEc) return;
    int src = eidx[e];
    int trg = eidx[EEc + e];
    int bid = bids[e];
    const float* Mb = M + bid * 256;
    const float4_* er = (const float4_*)(edges + (size_t)e * EDGE_DIM);
    float se0=0.f, se1=0.f, se2=0.f, se3=0.f;
    #pragma unroll
    for (int i = 0; i < 16; i++){
        float4_ v = er[i];
        #pragma unroll
        for (int c = 0; c < 4; c++){
            int d = i*4 + c;
            float4_ m = *(const float4_*)(Mb + d*4);
            se0 += v[c]*m[0];
            se1 += v[c]*m[1];
            se2 += v[c]*m[2];
            se3 += v[c]*m[3];
        }
    }
    float4_ ssv = *(const float4_*)(s_src + (size_t)src*4);
    float4_ stv = *(const float4_*)(s_trg + (size_t)trg*4);
    float sc0 = ssv[0] + stv[0] + se0;
    float sc1 = ssv[1] + stv[1] + se1;
    float sc2 = ssv[2] + stv[2] + se2;
    float sc3 = ssv[3] + stv[3] + se3;
    sc0 = sc0 > 0.f ? sc0 : 0.2f*sc0;
    sc1 = sc1 > 0.f ? sc1 : 0.2f*sc1;
    sc2 = sc2 > 0.f ? sc2 : 0.2f*sc2;
    sc3 = sc3 > 0.f ? sc3 : 0.2f*sc3;
    float4_ exv = {__expf(sc0), __expf(sc1), __expf(sc2), __expf(sc3)};
    *(float4_*)(ex + (size_t)e*4) = exv;

    int sl = atomicAdd(&cnt_src[src], 1);
    if (sl < CAP) adj_src[(size_t)src*CAP + sl] = (uint32_t)e;
    int sl2 = atomicAdd(&cnt_trg[trg], 1);
    if (sl2 < CAP) adj_trg[(size_t)trg*CAP + sl2] = (uint32_t)e;
}

// ---------------------------------------------------------------------------
// K5: fused aggregation (both directions) + softmax divide + skip + bias
//     + LayerNorm + fp32 store.  One wave per node; lane owns cols {2l,2l+1}
//     of each half.
// grid: 24000 blocks x 256 threads (4 waves/block)
// ---------------------------------------------------------------------------
__global__ __launch_bounds__(256) void k_agg(const ushortT* proj, const ushortT* skip,
    const float* bias, const float* ex, const int* eidx,
    const int* cnt_src, const int* cnt_trg,
    const uint32_t* adj_src, const uint32_t* adj_trg,
    const float* gamma, const float* beta, float* out)
{
    int wave = threadIdx.x >> 6, lane = threadIdx.x & 63;
    int n = blockIdx.x * 4 + wave;
    int h = lane >> 4;     // head of cols 2l,2l+1

    // skip + bias (shared by both halves)
    uint32_t sv = ((const uint32_t*)(skip + (size_t)n * 128))[lane];
    float sk0 = bf_lo(sv) + bias[2*lane];
    float sk1 = bf_hi(sv) + bias[2*lane + 1];

    // ---- src_feats (cols 0..127): edges with src==n, gather proj[trg] ----
    float a0 = 0.f, a1 = 0.f, ad = 0.f;
    {
        int cnt = cnt_src[n]; if (cnt > CAP) cnt = CAP;
        const uint32_t* ap = adj_src + (size_t)n * CAP;
        for (int i = 0; i < cnt; i++){
            int e = (int)ap[i];
            int nbr = eidx[EEc + e];             // trg of edge e
            float ev = ex[(size_t)e*4 + h];
            uint32_t pv = ((const uint32_t*)(proj + (size_t)nbr * 128))[lane];
            a0 += ev * bf_lo(pv);
            a1 += ev * bf_hi(pv);
            ad += ev;
        }
    }
    float inv = 1.f / (ad + 1e-16f);
    float f0 = a0 * inv + sk0;
    float f1 = a1 * inv + sk1;

    // ---- trg_feats (cols 128..255): edges with trg==n, gather proj[src] ----
    a0 = 0.f; a1 = 0.f; ad = 0.f;
    {
        int cnt = cnt_trg[n]; if (cnt > CAP) cnt = CAP;
        const uint32_t* ap = adj_trg + (size_t)n * CAP;
        for (int i = 0; i < cnt; i++){
            int e = (int)ap[i];
            int nbr = eidx[e];                   // src of edge e
            float ev = ex[(size_t)e*4 + h];
            uint32_t pv = ((const uint32_t*)(proj + (size_t)nbr * 128))[lane];
            a0 += ev * bf_lo(pv);
            a1 += ev * bf_hi(pv);
            ad += ev;
        }
    }
    inv = 1.f / (ad + 1e-16f);
    float f2 = a0 * inv + sk0;
    float f3 = a1 * inv + sk1;

    // ---- LayerNorm over the 256 concatenated features ----
    float s  = f0 + f1 + f2 + f3;
    float sq = f0*f0 + f1*f1 + f2*f2 + f3*f3;
    #pragma unroll
    for (int m = 1; m < 64; m <<= 1){
        s  += __shfl_xor(s,  m, 64);
        sq += __shfl_xor(sq, m, 64);
    }
    float mu  = s * (1.f/256.f);
    float var = sq * (1.f/256.f) - mu*mu;
    var = var < 0.f ? 0.f : var;
    float rr = rsqrtf(var + 1e-5f);

    float o0 = (f0 - mu) * rr * gamma[2*lane]       + beta[2*lane];
    float o1 = (f1 - mu) * rr * gamma[2*lane + 1]   + beta[2*lane + 1];
    float o2 = (f2 - mu) * rr * gamma[128 + 2*lane]     + beta[128 + 2*lane];
    float o3 = (f3 - mu) * rr * gamma[128 + 2*lane + 1] + beta[128 + 2*lane + 1];

    float* orow = out + (size_t)n * 256;
    *(float2*)(orow + 2*lane)       = make_float2(o0, o1);
    *(float2*)(orow + 128 + 2*lane) = make_float2(o2, o3);
}

// ---------------------------------------------------------------------------
extern "C" void kernel_launch(void* const* d_in, const int* in_sizes, int n_in,
                              void* d_out, int out_size, void* d_ws, size_t ws_size,
                              hipStream_t stream)
{
    const float* x      = (const float*)d_in[0];
    const int*   eidx   = (const int*)d_in[1];
    const float* edges  = (const float*)d_in[2];
    const float* ins    = (const float*)d_in[3];
    const int*   bids   = (const int*)d_in[4];
    const float* Wproj  = (const float*)d_in[6];
    const float* Wedge  = (const float*)d_in[7];
    const float* Wsrc   = (const float*)d_in[8];
    const float* bsrc   = (const float*)d_in[9];
    const float* Wtrg   = (const float*)d_in[10];
    const float* btrg   = (const float*)d_in[11];
    const float* Wedgi  = (const float*)d_in[12];
    const float* bedgi  = (const float*)d_in[13];
    const float* a_src  = (const float*)d_in[14];
    const float* a_trg  = (const float*)d_in[15];
    const float* a_edge = (const float*)d_in[16];
    const float* bias   = (const float*)d_in[17];
    const float* Wskip  = (const float*)d_in[18];
    const float* gamma  = (const float*)d_in[19];
    const float* beta   = (const float*)d_in[20];

    char* ws = (char*)d_ws;
    size_t off = 0;
    ushortT* proj  = (ushortT*)(ws + off); off += (size_t)NN * 128 * 2;   // 24.58 MB
    ushortT* skip  = (ushortT*)(ws + off); off += (size_t)NN * 128 * 2;   // 24.58 MB
    ushortT* WcatT = (ushortT*)(ws + off); off += 256 * 128 * 2;          // 64 KB
    float*   csrc  = (float*)(ws + off);   off += BB * HFD * 4;
    float*   ctrg  = (float*)(ws + off);   off += BB * HFD * 4;
    float*   M     = (float*)(ws + off);   off += BB * 256 * 4;
    float*   s_src = (float*)(ws + off);   off += (size_t)NN * 4 * 4;     // 1.54 MB
    float*   s_trg = (float*)(ws + off);   off += (size_t)NN * 4 * 4;     // 1.54 MB
    float*   ex    = (float*)(ws + off);   off += (size_t)EEc * 4 * 4;    // 9.6 MB
    int*     cnt_src = (int*)(ws + off);   off += (size_t)NN * 4;
    int*     cnt_trg = (int*)(ws + off);   off += (size_t)NN * 4;
    uint32_t* adj_src = (uint32_t*)(ws + off); off += (size_t)NN * CAP * 4;  // 12.29 MB
    uint32_t* adj_trg = (uint32_t*)(ws + off); off += (size_t)NN * CAP * 4;  // 12.29 MB
    // total ~87.4 MB

    hipMemsetAsync(cnt_src, 0, (size_t)NN * 4 * 2, stream);  // cnt_src+cnt_trg contiguous

    k_bridge<<<dim3(BB), dim3(128), 0, stream>>>(ins, Wsrc, bsrc, Wtrg, btrg, Wedgi, bedgi,
                                                 a_src, a_trg, a_edge, Wedge, csrc, ctrg, M);
    k_transpose<<<dim3(128), dim3(256), 0, stream>>>(Wproj, Wskip, WcatT);
    k_gemm<<<dim3(NN/64), dim3(256), 0, stream>>>(x, WcatT, proj, skip);
    k_scores<<<dim3(NN/256), dim3(256), 0, stream>>>(proj, csrc, ctrg, s_src, s_trg);
    k_edges<<<dim3((EEc + 255)/256), dim3(256), 0, stream>>>(eidx, bids, edges, M, s_src, s_trg,
                                                             ex, cnt_src, cnt_trg, adj_src, adj_trg);
    k_agg<<<dim3(NN/4), dim3(256), 0, stream>>>(proj, skip, bias, ex, eidx, cnt_src, cnt_trg,
                                                adj_src, adj_trg, gamma, beta, (float*)d_out);
}

// Round 3
// 603.224 us; speedup vs baseline: 1.1773x; 1.1773x over previous
//
#include <hip/hip_runtime.h>
#include <stdint.h>

typedef unsigned short ushortT;
typedef __attribute__((ext_vector_type(8))) short short8;
typedef __attribute__((ext_vector_type(4))) float float4_;

#define HH 4
#define FF 32
#define HFD 128
#define F_IN 128
#define EDGE_DIM 64
#define HIDDEN 256
#define BB 64
#define MLE 1500
#define NN 96000
#define EEc 600000
#define CAP 32

__device__ __forceinline__ float bf_lo(uint32_t u){ return __uint_as_float(u << 16); }
__device__ __forceinline__ float bf_hi(uint32_t u){ return __uint_as_float(u & 0xffff0000u); }
__device__ __forceinline__ uint32_t f2bf(float f){
    uint32_t u = __float_as_uint(f);
    return (u + 0x7fffu + ((u >> 16) & 1u)) >> 16;
}
__device__ __forceinline__ short8 cvt8(const float* p){
    float4_ x0 = *(const float4_*)p;
    float4_ x1 = *(const float4_*)(p + 4);
    short8 r;
    r[0]=(short)f2bf(x0[0]); r[1]=(short)f2bf(x0[1]); r[2]=(short)f2bf(x0[2]); r[3]=(short)f2bf(x0[3]);
    r[4]=(short)f2bf(x1[0]); r[5]=(short)f2bf(x1[1]); r[6]=(short)f2bf(x1[2]); r[7]=(short)f2bf(x1[3]);
    return r;
}

// ---------------------------------------------------------------------------
// K1: bridges (fp32).  csrc[b,hf]=(ins@Wsrc+bsrc)*a_src ; ctrg likewise.
//     cedge in LDS, then M[b,d,h] = sum_f W_edge[d,h*32+f] * cedge[b,h*32+f]
// grid: 64 blocks x 128 threads
// ---------------------------------------------------------------------------
__global__ void k_bridge(const float* ins, const float* Wsrc, const float* bsrc,
                         const float* Wtrg, const float* btrg,
                         const float* Wedg, const float* bedg,
                         const float* a_src, const float* a_trg, const float* a_edge,
                         const float* W_edge,
                         float* csrc, float* ctrg, float* Mout)
{
    __shared__ float ins_s[HIDDEN];
    __shared__ float ce_s[HFD];
    int b = blockIdx.x, t = threadIdx.x;  // t in [0,128)
    const float* ip = ins + b * HIDDEN;
    ins_s[t]       = ip[t];
    ins_s[t + 128] = ip[t + 128];
    __syncthreads();
    float as = 0.f, at = 0.f, ae = 0.f;
    for (int k = 0; k < HIDDEN; k++){
        float iv = ins_s[k];
        as += iv * Wsrc[k*HFD + t];
        at += iv * Wtrg[k*HFD + t];
        ae += iv * Wedg[k*HFD + t];
    }
    csrc[b*HFD + t] = (as + bsrc[t]) * a_src[t];
    ctrg[b*HFD + t] = (at + btrg[t]) * a_trg[t];
    ce_s[t] = (ae + bedg[t]) * a_edge[t];
    __syncthreads();
    #pragma unroll
    for (int rep = 0; rep < 2; rep++){
        int idx = t + rep * 128;      // 0..255
        int d = idx >> 2, h = idx & 3;
        float acc = 0.f;
        #pragma unroll
        for (int f = 0; f < FF; f++)
            acc += W_edge[d*HFD + h*FF + f] * ce_s[h*FF + f];
        Mout[b*256 + d*4 + h] = acc;
    }
}

// ---------------------------------------------------------------------------
// K_t: WcatT[c][d] = bf16( c<128 ? W_proj[d][c] : W_skip[d][c-128] )
// grid: 128 blocks x 256 threads
// ---------------------------------------------------------------------------
__global__ void k_transpose(const float* Wp, const float* Wsk, ushortT* WcatT)
{
    int idx = blockIdx.x * 256 + threadIdx.x;
    int c = idx >> 7;          // 0..255
    int d = idx & 127;         // 0..127
    float v = (c < 128) ? Wp[d*128 + c] : Wsk[d*128 + (c - 128)];
    WcatT[c*128 + d] = (ushortT)f2bf(v);
}

// ---------------------------------------------------------------------------
// K2: GEMM + fused scores.  A = WcatT (m=256 out-features), B = x^T
//     (n=16 nodes/wave).  D[m=feature][n=node]: lane n16 owns node,
//     reg r owns feature q*4+r of tile j -> packed 8B stores, and the
//     per-node score dot-products reduce across q via shfl_xor.
// grid: 1500 blocks x 256 threads
// ---------------------------------------------------------------------------
__global__ __launch_bounds__(256) void k_gemm(const float* x, const ushortT* WcatT,
                                              const float* csrc, const float* ctrg,
                                              ushortT* proj, ushortT* skip,
                                              float* s_src, float* s_trg)
{
    int t = threadIdx.x;
    int w = t >> 6, lane = t & 63;
    int q = lane >> 4, n16 = lane & 15;
    size_t node = (size_t)blockIdx.x * 64 + w * 16 + n16;

    float4_ acc[16];
    #pragma unroll
    for (int j = 0; j < 16; j++) acc[j] = (float4_){0.f, 0.f, 0.f, 0.f};

    #pragma unroll
    for (int kk = 0; kk < 4; kk++){
        short8 bfrag = cvt8(x + node * 128 + kk*32 + q*8);   // B[k][n=node]
        #pragma unroll
        for (int j = 0; j < 16; j++){
            short8 afrag = *(const short8*)(WcatT + (size_t)(j*16 + n16) * 128 + kk*32 + q*8);
            acc[j] = __builtin_amdgcn_mfma_f32_16x16x32_bf16(afrag, bfrag, acc[j], 0, 0, 0);
        }
    }

    // ---- store proj (j<8) / skip (j>=8): 8B packed per j ----
    #pragma unroll
    for (int j = 0; j < 16; j++){
        uint32_t p0 = f2bf(acc[j][0]) | (f2bf(acc[j][1]) << 16);
        uint32_t p1 = f2bf(acc[j][2]) | (f2bf(acc[j][3]) << 16);
        ushortT* base = (j < 8) ? (proj + node*128 + j*16 + q*4)
                                : (skip + node*128 + (j-8)*16 + q*4);
        uint2 pv; pv.x = p0; pv.y = p1;
        *(uint2*)base = pv;
    }

    // ---- fused scores: s[n,h] = sum_f proj_f32[n,h*32+f] * c[b,h*32+f] ----
    int b = (int)(node / MLE);
    const float* cs = csrc + b * HFD;
    const float* ct = ctrg + b * HFD;
    float ps[4] = {0,0,0,0}, pt[4] = {0,0,0,0};
    #pragma unroll
    for (int j = 0; j < 8; j++){
        int h = j >> 1;
        #pragma unroll
        for (int r = 0; r < 4; r++){
            int c = j*16 + q*4 + r;
            ps[h] += acc[j][r] * cs[c];
            pt[h] += acc[j][r] * ct[c];
        }
    }
    #pragma unroll
    for (int m = 16; m < 64; m <<= 1){
        #pragma unroll
        for (int hh = 0; hh < 4; hh++){
            ps[hh] += __shfl_xor(ps[hh], m, 64);
            pt[hh] += __shfl_xor(pt[hh], m, 64);
        }
    }
    float vs = (q == 0) ? ps[0] : (q == 1) ? ps[1] : (q == 2) ? ps[2] : ps[3];
    float vt = (q == 0) ? pt[0] : (q == 1) ? pt[1] : (q == 2) ? pt[2] : pt[3];
    s_src[node*4 + q] = vs;
    s_trg[node*4 + q] = vt;
}

// ---------------------------------------------------------------------------
// K4: per-edge scores + exp + adjacency build (edge-id-only entries).
// grid: ceil(E/256) x 256
// ---------------------------------------------------------------------------
__global__ __launch_bounds__(256) void k_edges(const int* eidx, const int* bids,
    const float* edges, const float* M, const float* s_src, const float* s_trg,
    float* ex, int* cnt_src, int* cnt_trg, uint32_t* adj_src, uint32_t* adj_trg)
{
    int e = blockIdx.x * 256 + threadIdx.x;
    if (e >= EEc) return;
    int src = eidx[e];
    int trg = eidx[EEc + e];
    int bid = bids[e];
    const float* Mb = M + bid * 256;
    const float4_* er = (const float4_*)(edges + (size_t)e * EDGE_DIM);
    float se0=0.f, se1=0.f, se2=0.f, se3=0.f;
    #pragma unroll
    for (int i = 0; i < 16; i++){
        float4_ v = er[i];
        #pragma unroll
        for (int c = 0; c < 4; c++){
            int d = i*4 + c;
            float4_ m = *(const float4_*)(Mb + d*4);
            se0 += v[c]*m[0];
            se1 += v[c]*m[1];
            se2 += v[c]*m[2];
            se3 += v[c]*m[3];
        }
    }
    float4_ ssv = *(const float4_*)(s_src + (size_t)src*4);
    float4_ stv = *(const float4_*)(s_trg + (size_t)trg*4);
    float sc0 = ssv[0] + stv[0] + se0;
    float sc1 = ssv[1] + stv[1] + se1;
    float sc2 = ssv[2] + stv[2] + se2;
    float sc3 = ssv[3] + stv[3] + se3;
    sc0 = sc0 > 0.f ? sc0 : 0.2f*sc0;
    sc1 = sc1 > 0.f ? sc1 : 0.2f*sc1;
    sc2 = sc2 > 0.f ? sc2 : 0.2f*sc2;
    sc3 = sc3 > 0.f ? sc3 : 0.2f*sc3;
    float4_ exv = {__expf(sc0), __expf(sc1), __expf(sc2), __expf(sc3)};
    *(float4_*)(ex + (size_t)e*4) = exv;

    int sl = atomicAdd(&cnt_src[src], 1);
    if (sl < CAP) adj_src[(size_t)src*CAP + sl] = (uint32_t)e;
    int sl2 = atomicAdd(&cnt_trg[trg], 1);
    if (sl2 < CAP) adj_trg[(size_t)trg*CAP + sl2] = (uint32_t)e;
}

// ---------------------------------------------------------------------------
// K5: fused aggregation + softmax + skip + bias + LayerNorm.
//     Two-phase: (1) lanes 0..cnt-1 stage (nbr, ex4) into LDS in parallel;
//     (2) main loop reads metadata from LDS (broadcast) -> proj gathers are
//     independent -> multiple outstanding vmem (MLP), unlike the old serial
//     adj->eidx->ex->proj chain.
// grid: 24000 blocks x 256 threads (one wave per node)
// ---------------------------------------------------------------------------
__global__ __launch_bounds__(256) void k_agg(const ushortT* proj, const ushortT* skip,
    const float* bias, const float* ex, const int* eidx,
    const int* cnt_src, const int* cnt_trg,
    const uint32_t* adj_src, const uint32_t* adj_trg,
    const float* gamma, const float* beta, float* out)
{
    __shared__ int   sh_nbr[2][4][CAP];
    __shared__ float sh_ev [2][4][CAP*4];

    int wave = threadIdx.x >> 6, lane = threadIdx.x & 63;
    int n = blockIdx.x * 4 + wave;
    int h = lane >> 4;

    int cnt0 = cnt_src[n]; if (cnt0 > CAP) cnt0 = CAP;
    int cnt1 = cnt_trg[n]; if (cnt1 > CAP) cnt1 = CAP;

    // phase 1: parallel metadata fetch into LDS
    if (lane < cnt0){
        int e = (int)adj_src[(size_t)n * CAP + lane];
        sh_nbr[0][wave][lane] = eidx[EEc + e];              // trg of edge
        *(float4_*)&sh_ev[0][wave][lane*4] = *(const float4_*)(ex + (size_t)e*4);
    }
    if (lane < cnt1){
        int e = (int)adj_trg[(size_t)n * CAP + lane];
        sh_nbr[1][wave][lane] = eidx[e];                    // src of edge
        *(float4_*)&sh_ev[1][wave][lane*4] = *(const float4_*)(ex + (size_t)e*4);
    }

    // skip + bias (issued before the barrier to overlap)
    uint32_t sv = ((const uint32_t*)(skip + (size_t)n * 128))[lane];
    float b0 = bias[2*lane], b1 = bias[2*lane + 1];

    __syncthreads();

    float sk0 = bf_lo(sv) + b0;
    float sk1 = bf_hi(sv) + b1;

    // phase 2a: src-direction aggregation (cols 0..127)
    float a0 = 0.f, a1 = 0.f, ad = 0.f;
    #pragma unroll 4
    for (int i = 0; i < cnt0; i++){
        int nbr  = sh_nbr[0][wave][i];
        float ev = sh_ev[0][wave][i*4 + h];
        uint32_t pv = ((const uint32_t*)(proj + (size_t)nbr * 128))[lane];
        a0 += ev * bf_lo(pv);
        a1 += ev * bf_hi(pv);
        ad += ev;
    }
    float inv = 1.f / (ad + 1e-16f);
    float f0 = a0 * inv + sk0;
    float f1 = a1 * inv + sk1;

    // phase 2b: trg-direction aggregation (cols 128..255)
    a0 = 0.f; a1 = 0.f; ad = 0.f;
    #pragma unroll 4
    for (int i = 0; i < cnt1; i++){
        int nbr  = sh_nbr[1][wave][i];
        float ev = sh_ev[1][wave][i*4 + h];
        uint32_t pv = ((const uint32_t*)(proj + (size_t)nbr * 128))[lane];
        a0 += ev * bf_lo(pv);
        a1 += ev * bf_hi(pv);
        ad += ev;
    }
    inv = 1.f / (ad + 1e-16f);
    float f2 = a0 * inv + sk0;
    float f3 = a1 * inv + sk1;

    // LayerNorm over 256 features
    float s  = f0 + f1 + f2 + f3;
    float sq = f0*f0 + f1*f1 + f2*f2 + f3*f3;
    #pragma unroll
    for (int m = 1; m < 64; m <<= 1){
        s  += __shfl_xor(s,  m, 64);
        sq += __shfl_xor(sq, m, 64);
    }
    float mu  = s * (1.f/256.f);
    float var = sq * (1.f/256.f) - mu*mu;
    var = var < 0.f ? 0.f : var;
    float rr = rsqrtf(var + 1e-5f);

    float o0 = (f0 - mu) * rr * gamma[2*lane]           + beta[2*lane];
    float o1 = (f1 - mu) * rr * gamma[2*lane + 1]       + beta[2*lane + 1];
    float o2 = (f2 - mu) * rr * gamma[128 + 2*lane]     + beta[128 + 2*lane];
    float o3 = (f3 - mu) * rr * gamma[128 + 2*lane + 1] + beta[128 + 2*lane + 1];

    float* orow = out + (size_t)n * 256;
    *(float2*)(orow + 2*lane)       = make_float2(o0, o1);
    *(float2*)(orow + 128 + 2*lane) = make_float2(o2, o3);
}

// ---------------------------------------------------------------------------
extern "C" void kernel_launch(void* const* d_in, const int* in_sizes, int n_in,
                              void* d_out, int out_size, void* d_ws, size_t ws_size,
                              hipStream_t stream)
{
    const float* x      = (const float*)d_in[0];
    const int*   eidx   = (const int*)d_in[1];
    const float* edges  = (const float*)d_in[2];
    const float* ins    = (const float*)d_in[3];
    const int*   bids   = (const int*)d_in[4];
    const float* Wproj  = (const float*)d_in[6];
    const float* Wedge  = (const float*)d_in[7];
    const float* Wsrc   = (const float*)d_in[8];
    const float* bsrc   = (const float*)d_in[9];
    const float* Wtrg   = (const float*)d_in[10];
    const float* btrg   = (const float*)d_in[11];
    const float* Wedgi  = (const float*)d_in[12];
    const float* bedgi  = (const float*)d_in[13];
    const float* a_src  = (const float*)d_in[14];
    const float* a_trg  = (const float*)d_in[15];
    const float* a_edge = (const float*)d_in[16];
    const float* bias   = (const float*)d_in[17];
    const float* Wskip  = (const float*)d_in[18];
    const float* gamma  = (const float*)d_in[19];
    const float* beta   = (const float*)d_in[20];

    char* ws = (char*)d_ws;
    size_t off = 0;
    ushortT* proj  = (ushortT*)(ws + off); off += (size_t)NN * 128 * 2;
    ushortT* skip  = (ushortT*)(ws + off); off += (size_t)NN * 128 * 2;
    ushortT* WcatT = (ushortT*)(ws + off); off += 256 * 128 * 2;
    float*   csrc  = (float*)(ws + off);   off += BB * HFD * 4;
    float*   ctrg  = (float*)(ws + off);   off += BB * HFD * 4;
    float*   M     = (float*)(ws + off);   off += BB * 256 * 4;
    float*   s_src = (float*)(ws + off);   off += (size_t)NN * 4 * 4;
    float*   s_trg = (float*)(ws + off);   off += (size_t)NN * 4 * 4;
    float*   ex    = (float*)(ws + off);   off += (size_t)EEc * 4 * 4;
    int*     cnt_src = (int*)(ws + off);   off += (size_t)NN * 4;
    int*     cnt_trg = (int*)(ws + off);   off += (size_t)NN * 4;
    uint32_t* adj_src = (uint32_t*)(ws + off); off += (size_t)NN * CAP * 4;
    uint32_t* adj_trg = (uint32_t*)(ws + off); off += (size_t)NN * CAP * 4;

    hipMemsetAsync(cnt_src, 0, (size_t)NN * 4 * 2, stream);  // cnt_src+cnt_trg contiguous

    k_bridge<<<dim3(BB), dim3(128), 0, stream>>>(ins, Wsrc, bsrc, Wtrg, btrg, Wedgi, bedgi,
                                                 a_src, a_trg, a_edge, Wedge, csrc, ctrg, M);
    k_transpose<<<dim3(128), dim3(256), 0, stream>>>(Wproj, Wskip, WcatT);
    k_gemm<<<dim3(NN/64), dim3(256), 0, stream>>>(x, WcatT, csrc, ctrg, proj, skip, s_src, s_trg);
    k_edges<<<dim3((EEc + 255)/256), dim3(256), 0, stream>>>(eidx, bids, edges, M, s_src, s_trg,
                                                             ex, cnt_src, cnt_trg, adj_src, adj_trg);
    k_agg<<<dim3(NN/4), dim3(256), 0, stream>>>(proj, skip, bias, ex, eidx, cnt_src, cnt_trg,
                                                adj_src, adj_trg, gamma, beta, (float*)d_out);
}